// Round 1
// baseline (244.573 us; speedup 1.0000x reference)
//
#include <hip/hip_runtime.h>

// SpectralMultiHeadAttention on MI355X (gfx950)
// b=4, hw=16384, c=256, heads=8, dh=32.
// Reformulation: S[b] = x^T x (256x256);  G = Wq^T S Wk;  qss = diag(Wq^T S Wq);
// kss = diag(Wk^T S Wk);  A = softmax(G_blocks / (nq nk sqrt(hw)));
// out = x @ (Wv @ Abig^T @ Wout).   q/k/v never materialized.

#define B_   4
#define HW_  16384
#define C_   256

typedef __attribute__((ext_vector_type(8))) short short8;
typedef __attribute__((ext_vector_type(4))) float floatx4;

__device__ __forceinline__ unsigned short f2bf(float f) {
  unsigned u = __builtin_bit_cast(unsigned, f);
  u += 0x7FFFu + ((u >> 16) & 1u);          // round-to-nearest-even
  return (unsigned short)(u >> 16);
}

__device__ __forceinline__ void gl_lds16(const unsigned short* g, unsigned short* l) {
  __builtin_amdgcn_global_load_lds(
      (const __attribute__((address_space(1))) unsigned int*)g,
      (__attribute__((address_space(3))) unsigned int*)l, 16, 0, 0);
}

// ---------------------------------------------------------------------------
// K1: cast fp32 -> bf16, emit xb (row-major [b*hw][c]) and xT ([b][c][hw]).
// grid 4096 = b(4) * ptile(256) * ctile(4), 256 thr. 64x64 tiles via LDS.
// ---------------------------------------------------------------------------
__global__ __launch_bounds__(256) void k_cast_tr(const float* __restrict__ x,
                                                 unsigned short* __restrict__ xb,
                                                 unsigned short* __restrict__ xT) {
  __shared__ unsigned short lds[64][72];
  int bid = blockIdx.x;
  int ct = bid & 3;
  int pt = (bid >> 2) & 255;
  int b  = bid >> 10;
  int t = threadIdx.x;
  const float* src = x + ((size_t)(b * HW_ + pt * 64)) * C_ + ct * 64;
#pragma unroll
  for (int e = 0; e < 4; e++) {
    int lin = t + e * 256;          // (p, c4)
    int p = lin >> 4, c4 = lin & 15;
    float4 v = *(const float4*)(src + (size_t)p * C_ + c4 * 4);
    ushort4 h;
    h.x = f2bf(v.x); h.y = f2bf(v.y); h.z = f2bf(v.z); h.w = f2bf(v.w);
    *(ushort4*)(xb + ((size_t)(b * HW_ + pt * 64 + p)) * C_ + ct * 64 + c4 * 4) = h;
    lds[c4 * 4 + 0][p] = h.x;
    lds[c4 * 4 + 1][p] = h.y;
    lds[c4 * 4 + 2][p] = h.z;
    lds[c4 * 4 + 3][p] = h.w;
  }
  __syncthreads();
#pragma unroll
  for (int e = 0; e < 4; e++) {
    int lin = t + e * 256;          // (c, p4)
    int c = lin >> 4, p4 = lin & 15;
    ushort4 h;
    h.x = lds[c][p4 * 4 + 0];
    h.y = lds[c][p4 * 4 + 1];
    h.z = lds[c][p4 * 4 + 2];
    h.w = lds[c][p4 * 4 + 3];
    *(ushort4*)(xT + ((size_t)(b * C_ + ct * 64 + c)) * HW_ + pt * 64 + p4 * 4) = h;
  }
}

// ---------------------------------------------------------------------------
// Shared MFMA NT main loop: C[128x128] += A_rows . B_rows (both K-contiguous).
// BK=64 per stage, 16x16x32 bf16 MFMA, 4 waves x (4x4 16-tiles) = 64x64/wave.
// LDS tiles [128 rows][64 k] bf16, staged via global_load_lds width-16 with
// xor-octet swizzle: LDS[row][o] holds global octet (o ^ (row&7)) so that
// ds_read_b128 fragment reads are bank-conflict-free.
// ---------------------------------------------------------------------------
template <int NST>
__device__ __forceinline__ void nt_loop(const unsigned short* Ab, int lda,
                                        const unsigned short* Bb, int ldb,
                                        unsigned short* At, unsigned short* Bt,
                                        floatx4 acc[4][4]) {
  int t = threadIdx.x;
  int lane = t & 63, w = t >> 6;
  int wm = w >> 1, wn = w & 1;
  int l8 = lane >> 3, l7 = lane & 7;
  int srcoct = l7 ^ l8;
  int l15 = lane & 15, l4 = lane >> 4;
  for (int s = 0; s < NST; s++) {
#pragma unroll
    for (int i = 0; i < 4; i++) {
      int gi = w * 4 + i;              // 16 issues per tile, 4 per wave
      int row = gi * 8 + l8;           // 8 rows per issue
      gl_lds16(Ab + (size_t)row * lda + s * 64 + srcoct * 8, At + gi * 512);
      gl_lds16(Bb + (size_t)row * ldb + s * 64 + srcoct * 8, Bt + gi * 512);
    }
    __syncthreads();
#pragma unroll
    for (int kk = 0; kk < 2; kk++) {   // 2 k-steps of 32 per BK=64
      short8 af[4], bfv[4];
#pragma unroll
      for (int tm = 0; tm < 4; tm++) {
        int row = wm * 64 + tm * 16 + l15;
        int oct = kk * 4 + l4;
        af[tm] = *(const short8*)(At + row * 64 + ((oct ^ (l15 & 7)) * 8));
      }
#pragma unroll
      for (int tn = 0; tn < 4; tn++) {
        int row = wn * 64 + tn * 16 + l15;
        int oct = kk * 4 + l4;
        bfv[tn] = *(const short8*)(Bt + row * 64 + ((oct ^ (l15 & 7)) * 8));
      }
#pragma unroll
      for (int tm = 0; tm < 4; tm++)
#pragma unroll
        for (int tn = 0; tn < 4; tn++)
          acc[tm][tn] = __builtin_amdgcn_mfma_f32_16x16x32_bf16(af[tm], bfv[tn],
                                                                acc[tm][tn], 0, 0, 0);
    }
    __syncthreads();
  }
}

// ---------------------------------------------------------------------------
// K2: S partials. grid 256 = b(4)*mt(2)*nt(2)*ks(16); each block: 128x128 tile
// over K-chunk 1024 of xT, writes fp32 partial tile.
// ---------------------------------------------------------------------------
__global__ __launch_bounds__(256) void k_sgemm(const unsigned short* __restrict__ xT,
                                               float* __restrict__ part) {
  __shared__ unsigned short At[128 * 64];
  __shared__ unsigned short Bt[128 * 64];
  int bid = blockIdx.x;
  int ks = bid & 15, nt = (bid >> 4) & 1, mt = (bid >> 5) & 1, b = bid >> 6;
  const unsigned short* Ab = xT + ((size_t)(b * C_ + mt * 128)) * HW_ + ks * 1024;
  const unsigned short* Bb = xT + ((size_t)(b * C_ + nt * 128)) * HW_ + ks * 1024;
  floatx4 acc[4][4];
  floatx4 z = {0.f, 0.f, 0.f, 0.f};
#pragma unroll
  for (int i = 0; i < 4; i++)
#pragma unroll
    for (int j = 0; j < 4; j++) acc[i][j] = z;
  nt_loop<16>(Ab, HW_, Bb, HW_, At, Bt, acc);
  int t = threadIdx.x, lane = t & 63, w = t >> 6;
  int wm = w >> 1, wn = w & 1;
  int l15 = lane & 15, l4 = lane >> 4;
  float* pb = part + ((size_t)((b * 4 + mt * 2 + nt) * 16 + ks)) * 16384;
#pragma unroll
  for (int tm = 0; tm < 4; tm++)
#pragma unroll
    for (int tn = 0; tn < 4; tn++)
#pragma unroll
      for (int r = 0; r < 4; r++) {
        int m = wm * 64 + tm * 16 + l4 * 4 + r;   // C/D: row=(lane>>4)*4+reg
        int n = wn * 64 + tn * 16 + l15;          //      col=lane&15
        pb[m * 128 + n] = acc[tm][tn][r];
      }
}

// K2r: reduce 16 K-partials -> S fp32 [b][256][256]. grid 1024*256.
__global__ __launch_bounds__(256) void k_sred(const float* __restrict__ part,
                                              float* __restrict__ S) {
  int idx = blockIdx.x * 256 + threadIdx.x;   // 0..262143
  int b = idx >> 16;
  int m = (idx >> 8) & 255, n = idx & 255;
  const float* p = part + ((size_t)((b * 4 + (m >> 7) * 2 + (n >> 7)) * 16)) * 16384
                   + (m & 127) * 128 + (n & 127);
  float s = 0.f;
#pragma unroll
  for (int k = 0; k < 16; k++) s += p[k * 16384];
  S[idx] = s;
}

// ---------------------------------------------------------------------------
// K3a: SWq = S@Wq, SWk = S@Wk (fp32, 64x64 tiles). grid 128 = b(4)*mt(4)*nt(8).
// ---------------------------------------------------------------------------
__global__ __launch_bounds__(256) void k_gemm_sw(const float* __restrict__ S,
                                                 const float* __restrict__ Wq,
                                                 const float* __restrict__ Wk,
                                                 float* __restrict__ SWq,
                                                 float* __restrict__ SWk) {
  __shared__ float As[64][17];
  __shared__ float Bs[16][65];
  int bid = blockIdx.x;
  int nt = bid & 7, mt = (bid >> 3) & 3, b = bid >> 5;
  int mb = mt * 64;
  const float* Wsel = (nt < 4) ? Wq : Wk;
  int nb = (nt & 3) * 64;
  int t = threadIdx.x, tx = t & 15, ty = t >> 4;
  float acc[4][4] = {};
  for (int kt = 0; kt < 16; kt++) {
    {
      int row = t >> 2, kq = t & 3;
      float4 v = *(const float4*)(S + ((size_t)(b * C_ + mb + row)) * C_ + kt * 16 + kq * 4);
      As[row][kq * 4 + 0] = v.x; As[row][kq * 4 + 1] = v.y;
      As[row][kq * 4 + 2] = v.z; As[row][kq * 4 + 3] = v.w;
    }
    {
      int kk = t >> 4, n4 = t & 15;
      float4 v = *(const float4*)(Wsel + ((size_t)(kt * 16 + kk)) * C_ + nb + n4 * 4);
      Bs[kk][n4 * 4 + 0] = v.x; Bs[kk][n4 * 4 + 1] = v.y;
      Bs[kk][n4 * 4 + 2] = v.z; Bs[kk][n4 * 4 + 3] = v.w;
    }
    __syncthreads();
#pragma unroll
    for (int k = 0; k < 16; k++) {
      float a[4], bb[4];
#pragma unroll
      for (int i = 0; i < 4; i++) a[i] = As[ty * 4 + i][k];
#pragma unroll
      for (int j = 0; j < 4; j++) bb[j] = Bs[k][tx * 4 + j];
#pragma unroll
      for (int i = 0; i < 4; i++)
#pragma unroll
        for (int j = 0; j < 4; j++) acc[i][j] += a[i] * bb[j];
    }
    __syncthreads();
  }
#pragma unroll
  for (int i = 0; i < 4; i++)
#pragma unroll
    for (int j = 0; j < 4; j++) {
      int row = mb + ty * 4 + i;
      int ng = nt * 64 + tx * 4 + j;
      if (ng < 256) SWq[((size_t)(b * C_ + row)) * C_ + ng] = acc[i][j];
      else          SWk[((size_t)(b * C_ + row)) * C_ + ng - 256] = acc[i][j];
    }
}

// ---------------------------------------------------------------------------
// K3b: Gf = Wq^T @ SWk (fp32, A transposed in staging). grid 64 = b*mt(4)*nt(4).
// ---------------------------------------------------------------------------
__global__ __launch_bounds__(256) void k_gemm_g(const float* __restrict__ Wq,
                                                const float* __restrict__ SWk,
                                                float* __restrict__ Gf) {
  __shared__ float As[64][17];
  __shared__ float Bs[16][65];
  int bid = blockIdx.x;
  int nt = bid & 3, mt = (bid >> 2) & 3, b = bid >> 4;
  int mb = mt * 64, nb = nt * 64;
  int t = threadIdx.x, tx = t & 15, ty = t >> 4;
  float acc[4][4] = {};
  for (int kt = 0; kt < 16; kt++) {
    {
      int kk = t >> 4, m4 = t & 15;   // load Wq[k][m], store transposed
      float4 v = *(const float4*)(Wq + ((size_t)(kt * 16 + kk)) * C_ + mb + m4 * 4);
      As[m4 * 4 + 0][kk] = v.x; As[m4 * 4 + 1][kk] = v.y;
      As[m4 * 4 + 2][kk] = v.z; As[m4 * 4 + 3][kk] = v.w;
    }
    {
      int kk = t >> 4, n4 = t & 15;
      float4 v = *(const float4*)(SWk + ((size_t)(b * C_ + kt * 16 + kk)) * C_ + nb + n4 * 4);
      Bs[kk][n4 * 4 + 0] = v.x; Bs[kk][n4 * 4 + 1] = v.y;
      Bs[kk][n4 * 4 + 2] = v.z; Bs[kk][n4 * 4 + 3] = v.w;
    }
    __syncthreads();
#pragma unroll
    for (int k = 0; k < 16; k++) {
      float a[4], bb[4];
#pragma unroll
      for (int i = 0; i < 4; i++) a[i] = As[ty * 4 + i][k];
#pragma unroll
      for (int j = 0; j < 4; j++) bb[j] = Bs[k][tx * 4 + j];
#pragma unroll
      for (int i = 0; i < 4; i++)
#pragma unroll
        for (int j = 0; j < 4; j++) acc[i][j] += a[i] * bb[j];
    }
    __syncthreads();
  }
#pragma unroll
  for (int i = 0; i < 4; i++)
#pragma unroll
    for (int j = 0; j < 4; j++)
      Gf[((size_t)(b * C_ + mb + ty * 4 + i)) * C_ + nb + tx * 4 + j] = acc[i][j];
}

// ---------------------------------------------------------------------------
// K3c: norms + softmax -> Aat[b][h][32][32]. grid 32 = (b,h), 256 thr.
// ---------------------------------------------------------------------------
__global__ __launch_bounds__(256) void k_softmax(const float* __restrict__ Wq,
                                                 const float* __restrict__ Wk,
                                                 const float* __restrict__ SWq,
                                                 const float* __restrict__ SWk,
                                                 const float* __restrict__ Gf,
                                                 float* __restrict__ Aat) {
  __shared__ float qpart[8][32], kpart[8][32], qin[32], kin[32], L[32][33];
  int b = blockIdx.x >> 3, h = blockIdx.x & 7;
  int t = threadIdx.x;
  int i = t & 31, part = t >> 5;
  float s = 0.f;
  for (int k = part * 32; k < part * 32 + 32; k++)
    s += Wq[(size_t)k * C_ + h * 32 + i] * SWq[((size_t)(b * C_ + k)) * C_ + h * 32 + i];
  qpart[part][i] = s;
  s = 0.f;
  for (int k = part * 32; k < part * 32 + 32; k++)
    s += Wk[(size_t)k * C_ + h * 32 + i] * SWk[((size_t)(b * C_ + k)) * C_ + h * 32 + i];
  kpart[part][i] = s;
  __syncthreads();
  if (t < 32) {
    float a = 0.f;
#pragma unroll
    for (int p = 0; p < 8; p++) a += qpart[p][t];
    qin[t] = rsqrtf(a);
  } else if (t < 64) {
    int j = t - 32;
    float a = 0.f;
#pragma unroll
    for (int p = 0; p < 8; p++) a += kpart[p][j];
    kin[j] = rsqrtf(a);
  }
  __syncthreads();
#pragma unroll
  for (int e = 0; e < 4; e++) {
    int idx = t + e * 256;
    int ii = idx >> 5, jj = idx & 31;
    float g = Gf[((size_t)(b * C_ + h * 32 + ii)) * C_ + h * 32 + jj];
    L[ii][jj] = g * qin[ii] * kin[jj] * 0.0078125f;   // / sqrt(16384)
  }
  __syncthreads();
  if (t < 32) {
    float mx = -1e30f;
#pragma unroll
    for (int j = 0; j < 32; j++) mx = fmaxf(mx, L[t][j]);
    float ex[32];
    float sum = 0.f;
#pragma unroll
    for (int j = 0; j < 32; j++) { ex[j] = __expf(L[t][j] - mx); sum += ex[j]; }
    float inv = 1.0f / sum;
#pragma unroll
    for (int j = 0; j < 32; j++)
      Aat[(((size_t)(b * 8 + h)) * 32 + t) * 32 + j] = ex[j] * inv;
  }
}

// ---------------------------------------------------------------------------
// K3d: T[b][h*32+j][n] = sum_i A_h[i][j] * Wout[h*32+i][n]. grid 32 = (b,h).
// ---------------------------------------------------------------------------
__global__ __launch_bounds__(256) void k_attn_t(const float* __restrict__ Aat,
                                                const float* __restrict__ Wout,
                                                float* __restrict__ T) {
  __shared__ float Ah[32][33];
  __shared__ float Wo[32][256];
  int b = blockIdx.x >> 3, h = blockIdx.x & 7;
  int t = threadIdx.x;
#pragma unroll
  for (int e = 0; e < 4; e++) {
    int idx = t + e * 256;
    int ii = idx >> 5, jj = idx & 31;
    Ah[ii][jj] = Aat[(((size_t)(b * 8 + h)) * 32 + ii) * 32 + jj];
  }
#pragma unroll
  for (int r = 0; r < 32; r++) Wo[r][t] = Wout[((size_t)(h * 32 + r)) * C_ + t];
  __syncthreads();
  for (int j = 0; j < 32; j++) {
    float a = 0.f;
#pragma unroll
    for (int i2 = 0; i2 < 32; i2++) a += Ah[i2][j] * Wo[i2][t];
    T[((size_t)(b * C_ + h * 32 + j)) * C_ + t] = a;
  }
}

// ---------------------------------------------------------------------------
// K3e: W3 = Wv @ T[b], emitted transposed bf16: W3bT[b][n][c]. grid 64.
// ---------------------------------------------------------------------------
__global__ __launch_bounds__(256) void k_gemm_w3(const float* __restrict__ Wv,
                                                 const float* __restrict__ T,
                                                 unsigned short* __restrict__ W3bT) {
  __shared__ float As[64][17];
  __shared__ float Bs[16][65];
  int bid = blockIdx.x;
  int nt = bid & 3, mt = (bid >> 2) & 3, b = bid >> 4;
  int mb = mt * 64, nb = nt * 64;
  int t = threadIdx.x, tx = t & 15, ty = t >> 4;
  float acc[4][4] = {};
  for (int kt = 0; kt < 16; kt++) {
    {
      int row = t >> 2, kq = t & 3;
      float4 v = *(const float4*)(Wv + ((size_t)(mb + row)) * C_ + kt * 16 + kq * 4);
      As[row][kq * 4 + 0] = v.x; As[row][kq * 4 + 1] = v.y;
      As[row][kq * 4 + 2] = v.z; As[row][kq * 4 + 3] = v.w;
    }
    {
      int kk = t >> 4, n4 = t & 15;
      float4 v = *(const float4*)(T + ((size_t)(b * C_ + kt * 16 + kk)) * C_ + nb + n4 * 4);
      Bs[kk][n4 * 4 + 0] = v.x; Bs[kk][n4 * 4 + 1] = v.y;
      Bs[kk][n4 * 4 + 2] = v.z; Bs[kk][n4 * 4 + 3] = v.w;
    }
    __syncthreads();
#pragma unroll
    for (int k = 0; k < 16; k++) {
      float a[4], bb[4];
#pragma unroll
      for (int i = 0; i < 4; i++) a[i] = As[ty * 4 + i][k];
#pragma unroll
      for (int j = 0; j < 4; j++) bb[j] = Bs[k][tx * 4 + j];
#pragma unroll
      for (int i = 0; i < 4; i++)
#pragma unroll
        for (int j = 0; j < 4; j++) acc[i][j] += a[i] * bb[j];
    }
    __syncthreads();
  }
#pragma unroll
  for (int i = 0; i < 4; i++)
#pragma unroll
    for (int j = 0; j < 4; j++)
      W3bT[((size_t)(b * C_ + nb + tx * 4 + j)) * C_ + mb + ty * 4 + i] = f2bf(acc[i][j]);
}

// ---------------------------------------------------------------------------
// K4: out = xb @ W3[b], fp32 out. grid 1024 = mtile(512)*ntile(2).
// ---------------------------------------------------------------------------
__global__ __launch_bounds__(256) void k_out(const unsigned short* __restrict__ xb,
                                             const unsigned short* __restrict__ W3bT,
                                             float* __restrict__ out) {
  __shared__ unsigned short At[128 * 64];
  __shared__ unsigned short Bt[128 * 64];
  int bid = blockIdx.x;
  int ntile = bid & 1, mtile = bid >> 1;
  int b = mtile >> 7;
  const unsigned short* Ab = xb + (size_t)mtile * 128 * C_;
  const unsigned short* Bb = W3bT + ((size_t)(b * C_ + ntile * 128)) * C_;
  floatx4 acc[4][4];
  floatx4 z = {0.f, 0.f, 0.f, 0.f};
#pragma unroll
  for (int i = 0; i < 4; i++)
#pragma unroll
    for (int j = 0; j < 4; j++) acc[i][j] = z;
  nt_loop<4>(Ab, C_, Bb, C_, At, Bt, acc);
  int t = threadIdx.x, lane = t & 63, w = t >> 6;
  int wm = w >> 1, wn = w & 1;
  int l15 = lane & 15, l4 = lane >> 4;
  float* ob = out + (size_t)mtile * 128 * C_ + ntile * 128;
#pragma unroll
  for (int tm = 0; tm < 4; tm++)
#pragma unroll
    for (int tn = 0; tn < 4; tn++)
#pragma unroll
      for (int r = 0; r < 4; r++) {
        int m = wm * 64 + tm * 16 + l4 * 4 + r;
        int n = wn * 64 + tn * 16 + l15;
        ob[(size_t)m * C_ + n] = acc[tm][tn][r];
      }
}

// ---------------------------------------------------------------------------
extern "C" void kernel_launch(void* const* d_in, const int* in_sizes, int n_in,
                              void* d_out, int out_size, void* d_ws, size_t ws_size,
                              hipStream_t stream) {
  const float* x    = (const float*)d_in[0];
  const float* Wq   = (const float*)d_in[1];
  const float* Wk   = (const float*)d_in[2];
  const float* Wv   = (const float*)d_in[3];
  const float* Wout = (const float*)d_in[4];
  float* out = (float*)d_out;

  // workspace carve-up (~85.6 MiB)
  unsigned short* xT = (unsigned short*)d_ws;          // 4*256*16384 bf16 = 32 MiB
  unsigned short* xb = xT + (size_t)16777216;          // 32 MiB
  float* part = (float*)(xb + (size_t)16777216);       // 4*4*16*16384 fp32 = 16 MiB
  float* S    = part + (size_t)4194304;                // 1 MiB
  float* SWq  = S + 262144;                            // 1 MiB
  float* SWk  = SWq + 262144;                          // 1 MiB
  float* Gf   = SWk + 262144;                          // 1 MiB
  float* Aat  = Gf + 262144;                           // 128 KiB
  float* T    = Aat + 32768;                           // 1 MiB
  unsigned short* W3bT = (unsigned short*)(T + 262144); // 512 KiB

  k_cast_tr<<<dim3(4096), dim3(256), 0, stream>>>(x, xb, xT);
  k_sgemm<<<dim3(256), dim3(256), 0, stream>>>(xT, part);
  k_sred<<<dim3(1024), dim3(256), 0, stream>>>(part, S);
  k_gemm_sw<<<dim3(128), dim3(256), 0, stream>>>(S, Wq, Wk, SWq, SWk);
  k_gemm_g<<<dim3(64), dim3(256), 0, stream>>>(Wq, SWk, Gf);
  k_softmax<<<dim3(32), dim3(256), 0, stream>>>(Wq, Wk, SWq, SWk, Gf, Aat);
  k_attn_t<<<dim3(32), dim3(256), 0, stream>>>(Aat, Wout, T);
  k_gemm_w3<<<dim3(64), dim3(256), 0, stream>>>(Wv, T, W3bT);
  k_out<<<dim3(1024), dim3(256), 0, stream>>>(xb, W3bT, out);
}

// Round 2
// 240.466 us; speedup vs baseline: 1.0171x; 1.0171x over previous
//
#include <hip/hip_runtime.h>

// SpectralMultiHeadAttention on MI355X (gfx950)
// b=4, hw=16384, c=256, heads=8, dh=32.
// Reformulation: S[b] = x^T x (256x256);  G = Wq^T S Wk;  qss = diag(Wq^T S Wq);
// kss = diag(Wk^T S Wk);  A = softmax(G_blocks / (nq nk sqrt(hw)));
// out = x @ (Wv @ Abig^T @ Wout).   q/k/v never materialized.
// R2: K2 k-split 32 + fp32 atomicAdd into S (part buffer + k_sred gone);
//     G/softmax/U chain fused into one kernel. 9 dispatches -> 6.

#define B_   4
#define HW_  16384
#define C_   256

typedef __attribute__((ext_vector_type(8))) short short8;
typedef __attribute__((ext_vector_type(4))) float floatx4;

__device__ __forceinline__ unsigned short f2bf(float f) {
  unsigned u = __builtin_bit_cast(unsigned, f);
  u += 0x7FFFu + ((u >> 16) & 1u);          // round-to-nearest-even
  return (unsigned short)(u >> 16);
}

__device__ __forceinline__ void gl_lds16(const unsigned short* g, unsigned short* l) {
  __builtin_amdgcn_global_load_lds(
      (const __attribute__((address_space(1))) unsigned int*)g,
      (__attribute__((address_space(3))) unsigned int*)l, 16, 0, 0);
}

// ---------------------------------------------------------------------------
// K1: cast fp32 -> bf16, emit xb (row-major [b*hw][c]) and xT ([b][c][hw]).
// Also zeroes S (ws is poisoned 0xAA each call; K2 accumulates atomically).
// grid 4096 = b(4) * ptile(256) * ctile(4), 256 thr. 64x64 tiles via LDS.
// ---------------------------------------------------------------------------
__global__ __launch_bounds__(256) void k_cast_tr(const float* __restrict__ x,
                                                 unsigned short* __restrict__ xb,
                                                 unsigned short* __restrict__ xT,
                                                 float* __restrict__ S) {
  __shared__ unsigned short lds[64][72];
  int bid = blockIdx.x;
  int t = threadIdx.x;
  if (bid < 256) {                       // zero S: 256 blk * 256 thr * 16B = 1 MiB
    float4 z = {0.f, 0.f, 0.f, 0.f};
    ((float4*)S)[bid * 256 + t] = z;
  }
  int ct = bid & 3;
  int pt = (bid >> 2) & 255;
  int b  = bid >> 10;
  const float* src = x + ((size_t)(b * HW_ + pt * 64)) * C_ + ct * 64;
#pragma unroll
  for (int e = 0; e < 4; e++) {
    int lin = t + e * 256;          // (p, c4)
    int p = lin >> 4, c4 = lin & 15;
    float4 v = *(const float4*)(src + (size_t)p * C_ + c4 * 4);
    ushort4 h;
    h.x = f2bf(v.x); h.y = f2bf(v.y); h.z = f2bf(v.z); h.w = f2bf(v.w);
    *(ushort4*)(xb + ((size_t)(b * HW_ + pt * 64 + p)) * C_ + ct * 64 + c4 * 4) = h;
    lds[c4 * 4 + 0][p] = h.x;
    lds[c4 * 4 + 1][p] = h.y;
    lds[c4 * 4 + 2][p] = h.z;
    lds[c4 * 4 + 3][p] = h.w;
  }
  __syncthreads();
#pragma unroll
  for (int e = 0; e < 4; e++) {
    int lin = t + e * 256;          // (c, p4)
    int c = lin >> 4, p4 = lin & 15;
    ushort4 h;
    h.x = lds[c][p4 * 4 + 0];
    h.y = lds[c][p4 * 4 + 1];
    h.z = lds[c][p4 * 4 + 2];
    h.w = lds[c][p4 * 4 + 3];
    *(ushort4*)(xT + ((size_t)(b * C_ + ct * 64 + c)) * HW_ + pt * 64 + p4 * 4) = h;
  }
}

// ---------------------------------------------------------------------------
// Shared MFMA NT main loop: C[128x128] += A_rows . B_rows (both K-contiguous).
// BK=64 per stage, 16x16x32 bf16 MFMA, 4 waves x (4x4 16-tiles) = 64x64/wave.
// LDS tiles [128 rows][64 k] bf16, staged via global_load_lds width-16 with
// xor-octet swizzle: LDS[row][o] holds global octet (o ^ (row&7)) so that
// ds_read_b128 fragment reads are bank-conflict-free.
// ---------------------------------------------------------------------------
template <int NST>
__device__ __forceinline__ void nt_loop(const unsigned short* Ab, int lda,
                                        const unsigned short* Bb, int ldb,
                                        unsigned short* At, unsigned short* Bt,
                                        floatx4 acc[4][4]) {
  int t = threadIdx.x;
  int lane = t & 63, w = t >> 6;
  int wm = w >> 1, wn = w & 1;
  int l8 = lane >> 3, l7 = lane & 7;
  int srcoct = l7 ^ l8;
  int l15 = lane & 15, l4 = lane >> 4;
  for (int s = 0; s < NST; s++) {
#pragma unroll
    for (int i = 0; i < 4; i++) {
      int gi = w * 4 + i;              // 16 issues per tile, 4 per wave
      int row = gi * 8 + l8;           // 8 rows per issue
      gl_lds16(Ab + (size_t)row * lda + s * 64 + srcoct * 8, At + gi * 512);
      gl_lds16(Bb + (size_t)row * ldb + s * 64 + srcoct * 8, Bt + gi * 512);
    }
    __syncthreads();
#pragma unroll
    for (int kk = 0; kk < 2; kk++) {   // 2 k-steps of 32 per BK=64
      short8 af[4], bfv[4];
#pragma unroll
      for (int tm = 0; tm < 4; tm++) {
        int row = wm * 64 + tm * 16 + l15;
        int oct = kk * 4 + l4;
        af[tm] = *(const short8*)(At + row * 64 + ((oct ^ (l15 & 7)) * 8));
      }
#pragma unroll
      for (int tn = 0; tn < 4; tn++) {
        int row = wn * 64 + tn * 16 + l15;
        int oct = kk * 4 + l4;
        bfv[tn] = *(const short8*)(Bt + row * 64 + ((oct ^ (l15 & 7)) * 8));
      }
#pragma unroll
      for (int tm = 0; tm < 4; tm++)
#pragma unroll
        for (int tn = 0; tn < 4; tn++)
          acc[tm][tn] = __builtin_amdgcn_mfma_f32_16x16x32_bf16(af[tm], bfv[tn],
                                                                acc[tm][tn], 0, 0, 0);
    }
    __syncthreads();
  }
}

// ---------------------------------------------------------------------------
// K2: S via atomics. grid 512 = b(4)*mt(2)*nt(2)*ks(32); each block: 128x128
// tile over hw-chunk of 512, atomicAdd fp32 into S (zeroed by K1).
// 512 blocks = 2 blocks/CU for latency hiding (was 1 at ks=16).
// ---------------------------------------------------------------------------
__global__ __launch_bounds__(256) void k_sgemm(const unsigned short* __restrict__ xT,
                                               float* __restrict__ S) {
  __shared__ unsigned short At[128 * 64];
  __shared__ unsigned short Bt[128 * 64];
  int bid = blockIdx.x;
  int ks = bid & 31, nt = (bid >> 5) & 1, mt = (bid >> 6) & 1, b = bid >> 7;
  const unsigned short* Ab = xT + ((size_t)(b * C_ + mt * 128)) * HW_ + ks * 512;
  const unsigned short* Bb = xT + ((size_t)(b * C_ + nt * 128)) * HW_ + ks * 512;
  floatx4 acc[4][4];
  floatx4 z = {0.f, 0.f, 0.f, 0.f};
#pragma unroll
  for (int i = 0; i < 4; i++)
#pragma unroll
    for (int j = 0; j < 4; j++) acc[i][j] = z;
  nt_loop<8>(Ab, HW_, Bb, HW_, At, Bt, acc);
  int t = threadIdx.x, lane = t & 63, w = t >> 6;
  int wm = w >> 1, wn = w & 1;
  int l15 = lane & 15, l4 = lane >> 4;
  float* Sb = S + (size_t)b * 65536;
#pragma unroll
  for (int tm = 0; tm < 4; tm++)
#pragma unroll
    for (int tn = 0; tn < 4; tn++)
#pragma unroll
      for (int r = 0; r < 4; r++) {
        int m = mt * 128 + wm * 64 + tm * 16 + l4 * 4 + r;  // C/D: row=(lane>>4)*4+reg
        int n = nt * 128 + wn * 64 + tn * 16 + l15;         //      col=lane&15
        atomicAdd(Sb + (size_t)m * C_ + n, acc[tm][tn][r]);
      }
}

// ---------------------------------------------------------------------------
// K3a: SWq = S@Wq, SWk = S@Wk (fp32, 64x64 tiles). grid 128 = b(4)*mt(4)*nt(8).
// ---------------------------------------------------------------------------
__global__ __launch_bounds__(256) void k_gemm_sw(const float* __restrict__ S,
                                                 const float* __restrict__ Wq,
                                                 const float* __restrict__ Wk,
                                                 float* __restrict__ SWq,
                                                 float* __restrict__ SWk) {
  __shared__ float As[64][17];
  __shared__ float Bs[16][65];
  int bid = blockIdx.x;
  int nt = bid & 7, mt = (bid >> 3) & 3, b = bid >> 5;
  int mb = mt * 64;
  const float* Wsel = (nt < 4) ? Wq : Wk;
  int nb = (nt & 3) * 64;
  int t = threadIdx.x, tx = t & 15, ty = t >> 4;
  float acc[4][4] = {};
  for (int kt = 0; kt < 16; kt++) {
    {
      int row = t >> 2, kq = t & 3;
      float4 v = *(const float4*)(S + ((size_t)(b * C_ + mb + row)) * C_ + kt * 16 + kq * 4);
      As[row][kq * 4 + 0] = v.x; As[row][kq * 4 + 1] = v.y;
      As[row][kq * 4 + 2] = v.z; As[row][kq * 4 + 3] = v.w;
    }
    {
      int kk = t >> 4, n4 = t & 15;
      float4 v = *(const float4*)(Wsel + ((size_t)(kt * 16 + kk)) * C_ + nb + n4 * 4);
      Bs[kk][n4 * 4 + 0] = v.x; Bs[kk][n4 * 4 + 1] = v.y;
      Bs[kk][n4 * 4 + 2] = v.z; Bs[kk][n4 * 4 + 3] = v.w;
    }
    __syncthreads();
#pragma unroll
    for (int k = 0; k < 16; k++) {
      float a[4], bb[4];
#pragma unroll
      for (int i = 0; i < 4; i++) a[i] = As[ty * 4 + i][k];
#pragma unroll
      for (int j = 0; j < 4; j++) bb[j] = Bs[k][tx * 4 + j];
#pragma unroll
      for (int i = 0; i < 4; i++)
#pragma unroll
        for (int j = 0; j < 4; j++) acc[i][j] += a[i] * bb[j];
    }
    __syncthreads();
  }
#pragma unroll
  for (int i = 0; i < 4; i++)
#pragma unroll
    for (int j = 0; j < 4; j++) {
      int row = mb + ty * 4 + i;
      int ng = nt * 64 + tx * 4 + j;
      if (ng < 256) SWq[((size_t)(b * C_ + row)) * C_ + ng] = acc[i][j];
      else          SWk[((size_t)(b * C_ + row)) * C_ + ng - 256] = acc[i][j];
    }
}

// ---------------------------------------------------------------------------
// K3f: fused G_h + norms + softmax + U_h. grid 32 = (b,h), 256 thr.
//   G_h[i][j]  = sum_k Wq[k][h32+i] * SWk[b][k][h32+j]
//   qss[i]     = sum_k Wq[k][h32+i] * SWq[b][k][h32+i]   (kss analogous)
//   A_h        = softmax(G_h * qin_i * kin_j / 128)  rows
//   U[h32+j][n]= sum_i A_h[i][j] * Wout[h32+i][n]
// ---------------------------------------------------------------------------
__global__ __launch_bounds__(256) void k_fuse(const float* __restrict__ Wq,
                                              const float* __restrict__ Wk,
                                              const float* __restrict__ SWq,
                                              const float* __restrict__ SWk,
                                              const float* __restrict__ Wout,
                                              float* __restrict__ U) {
  __shared__ float Wqh[256][32];    // 32 KiB (reused as Wo[32][256] for U phase)
  __shared__ float Wkh[256][32];
  __shared__ float SWqh[256][32];
  __shared__ float SWkh[256][32];   // total 128 KiB
  __shared__ float Lg[32][33];
  __shared__ float qp[8][32], kp[8][32], qin[32], kin[32];
  int b = blockIdx.x >> 3, h = blockIdx.x & 7;
  int t = threadIdx.x;
  int col = t & 31, rgrp = t >> 5;               // 8 rows per sweep
  // stage the four 256x32 h-slices (coalesced 128B segments per row)
  for (int r0 = 0; r0 < 256; r0 += 8) {
    int row = r0 + rgrp;
    Wqh[row][col]  = Wq[(size_t)row * C_ + h * 32 + col];
    Wkh[row][col]  = Wk[(size_t)row * C_ + h * 32 + col];
    SWqh[row][col] = SWq[((size_t)(b * C_ + row)) * C_ + h * 32 + col];
    SWkh[row][col] = SWk[((size_t)(b * C_ + row)) * C_ + h * 32 + col];
  }
  __syncthreads();
  // G: thread (rgrp, col=j) computes i = rgrp + 8*r, r=0..3
  {
    float g[4] = {0.f, 0.f, 0.f, 0.f};
    for (int k = 0; k < 256; k++) {
      float swk = SWkh[k][col];
#pragma unroll
      for (int r = 0; r < 4; r++) g[r] += Wqh[k][rgrp + 8 * r] * swk;
    }
#pragma unroll
    for (int r = 0; r < 4; r++) Lg[rgrp + 8 * r][col] = g[r];
  }
  // diag partials: thread (p=rgrp, i=col)
  {
    float sq = 0.f, sk = 0.f;
    for (int k = rgrp * 32; k < rgrp * 32 + 32; k++) {
      sq += Wqh[k][col] * SWqh[k][col];
      sk += Wkh[k][col] * SWkh[k][col];
    }
    qp[rgrp][col] = sq;
    kp[rgrp][col] = sk;
  }
  __syncthreads();
  if (t < 32) {
    float a = 0.f;
#pragma unroll
    for (int p = 0; p < 8; p++) a += qp[p][t];
    qin[t] = rsqrtf(a);
  } else if (t < 64) {
    int j = t - 32;
    float a = 0.f;
#pragma unroll
    for (int p = 0; p < 8; p++) a += kp[p][j];
    kin[j] = rsqrtf(a);
  }
  __syncthreads();
  // softmax rows (in place in Lg)
  if (t < 32) {
    float row[32];
    float mx = -1e30f;
#pragma unroll
    for (int j = 0; j < 32; j++) {
      row[j] = Lg[t][j] * qin[t] * kin[j] * 0.0078125f;   // /sqrt(16384)
      mx = fmaxf(mx, row[j]);
    }
    float sum = 0.f;
#pragma unroll
    for (int j = 0; j < 32; j++) { row[j] = __expf(row[j] - mx); sum += row[j]; }
    float inv = 1.0f / sum;
#pragma unroll
    for (int j = 0; j < 32; j++) Lg[t][j] = row[j] * inv;
  }
  __syncthreads();
  // repurpose Wqh's 32 KiB as Wo[32][256]
  float (*Wo)[256] = reinterpret_cast<float(*)[256]>(&Wqh[0][0]);
#pragma unroll
  for (int r = 0; r < 32; r++) Wo[r][t] = Wout[((size_t)(h * 32 + r)) * C_ + t];
  __syncthreads();
  for (int j = 0; j < 32; j++) {
    float a = 0.f;
#pragma unroll
    for (int i2 = 0; i2 < 32; i2++) a += Lg[i2][j] * Wo[i2][t];
    U[((size_t)(b * C_ + h * 32 + j)) * C_ + t] = a;
  }
}

// ---------------------------------------------------------------------------
// K3e: W3 = Wv @ U[b], emitted transposed bf16: W3bT[b][n][c]. grid 64.
// ---------------------------------------------------------------------------
__global__ __launch_bounds__(256) void k_gemm_w3(const float* __restrict__ Wv,
                                                 const float* __restrict__ U,
                                                 unsigned short* __restrict__ W3bT) {
  __shared__ float As[64][17];
  __shared__ float Bs[16][65];
  int bid = blockIdx.x;
  int nt = bid & 3, mt = (bid >> 2) & 3, b = bid >> 4;
  int mb = mt * 64, nb = nt * 64;
  int t = threadIdx.x, tx = t & 15, ty = t >> 4;
  float acc[4][4] = {};
  for (int kt = 0; kt < 16; kt++) {
    {
      int row = t >> 2, kq = t & 3;
      float4 v = *(const float4*)(Wv + ((size_t)(mb + row)) * C_ + kt * 16 + kq * 4);
      As[row][kq * 4 + 0] = v.x; As[row][kq * 4 + 1] = v.y;
      As[row][kq * 4 + 2] = v.z; As[row][kq * 4 + 3] = v.w;
    }
    {
      int kk = t >> 4, n4 = t & 15;
      float4 v = *(const float4*)(U + ((size_t)(b * C_ + kt * 16 + kk)) * C_ + nb + n4 * 4);
      Bs[kk][n4 * 4 + 0] = v.x; Bs[kk][n4 * 4 + 1] = v.y;
      Bs[kk][n4 * 4 + 2] = v.z; Bs[kk][n4 * 4 + 3] = v.w;
    }
    __syncthreads();
#pragma unroll
    for (int k = 0; k < 16; k++) {
      float a[4], bb[4];
#pragma unroll
      for (int i = 0; i < 4; i++) a[i] = As[ty * 4 + i][k];
#pragma unroll
      for (int j = 0; j < 4; j++) bb[j] = Bs[k][tx * 4 + j];
#pragma unroll
      for (int i = 0; i < 4; i++)
#pragma unroll
        for (int j = 0; j < 4; j++) acc[i][j] += a[i] * bb[j];
    }
    __syncthreads();
  }
#pragma unroll
  for (int i = 0; i < 4; i++)
#pragma unroll
    for (int j = 0; j < 4; j++)
      W3bT[((size_t)(b * C_ + nb + tx * 4 + j)) * C_ + mb + ty * 4 + i] = f2bf(acc[i][j]);
}

// ---------------------------------------------------------------------------
// K4: out = xb @ W3[b], fp32 out. grid 1024 = mtile(512)*ntile(2).
// ---------------------------------------------------------------------------
__global__ __launch_bounds__(256) void k_out(const unsigned short* __restrict__ xb,
                                             const unsigned short* __restrict__ W3bT,
                                             float* __restrict__ out) {
  __shared__ unsigned short At[128 * 64];
  __shared__ unsigned short Bt[128 * 64];
  int bid = blockIdx.x;
  int ntile = bid & 1, mtile = bid >> 1;
  int b = mtile >> 7;
  const unsigned short* Ab = xb + (size_t)mtile * 128 * C_;
  const unsigned short* Bb = W3bT + ((size_t)(b * C_ + ntile * 128)) * C_;
  floatx4 acc[4][4];
  floatx4 z = {0.f, 0.f, 0.f, 0.f};
#pragma unroll
  for (int i = 0; i < 4; i++)
#pragma unroll
    for (int j = 0; j < 4; j++) acc[i][j] = z;
  nt_loop<4>(Ab, C_, Bb, C_, At, Bt, acc);
  int t = threadIdx.x, lane = t & 63, w = t >> 6;
  int wm = w >> 1, wn = w & 1;
  int l15 = lane & 15, l4 = lane >> 4;
  float* ob = out + (size_t)mtile * 128 * C_ + ntile * 128;
#pragma unroll
  for (int tm = 0; tm < 4; tm++)
#pragma unroll
    for (int tn = 0; tn < 4; tn++)
#pragma unroll
      for (int r = 0; r < 4; r++) {
        int m = wm * 64 + tm * 16 + l4 * 4 + r;
        int n = wn * 64 + tn * 16 + l15;
        ob[(size_t)m * C_ + n] = acc[tm][tn][r];
      }
}

// ---------------------------------------------------------------------------
extern "C" void kernel_launch(void* const* d_in, const int* in_sizes, int n_in,
                              void* d_out, int out_size, void* d_ws, size_t ws_size,
                              hipStream_t stream) {
  const float* x    = (const float*)d_in[0];
  const float* Wq   = (const float*)d_in[1];
  const float* Wk   = (const float*)d_in[2];
  const float* Wv   = (const float*)d_in[3];
  const float* Wout = (const float*)d_in[4];
  float* out = (float*)d_out;

  // workspace carve-up (~69 MiB)
  unsigned short* xT = (unsigned short*)d_ws;          // 4*256*16384 bf16 = 32 MiB
  unsigned short* xb = xT + (size_t)16777216;          // 32 MiB
  float* S    = (float*)(xb + (size_t)16777216);       // 1 MiB
  float* SWq  = S + 262144;                            // 1 MiB
  float* SWk  = SWq + 262144;                          // 1 MiB
  float* U    = SWk + 262144;                          // 1 MiB
  unsigned short* W3bT = (unsigned short*)(U + 262144); // 512 KiB

  k_cast_tr<<<dim3(4096), dim3(256), 0, stream>>>(x, xb, xT, S);
  k_sgemm<<<dim3(512), dim3(256), 0, stream>>>(xT, S);
  k_gemm_sw<<<dim3(128), dim3(256), 0, stream>>>(S, Wq, Wk, SWq, SWk);
  k_fuse<<<dim3(32), dim3(256), 0, stream>>>(Wq, Wk, SWq, SWk, Wout, U);
  k_gemm_w3<<<dim3(64), dim3(256), 0, stream>>>(Wv, U, W3bT);
  k_out<<<dim3(1024), dim3(256), 0, stream>>>(xb, W3bT, out);
}

// Round 3
// 232.263 us; speedup vs baseline: 1.0530x; 1.0353x over previous
//
#include <hip/hip_runtime.h>

// SpectralMultiHeadAttention on MI355X (gfx950)
// b=4, hw=16384, c=256, heads=8, dh=32.
// Reformulation: S[b] = x^T x (256x256);  G = Wq^T S Wk;  qss = diag(Wq^T S Wq);
// kss = diag(Wk^T S Wk);  A = softmax(G_blocks / (nq nk sqrt(hw)));
// out = x @ (Wv @ Abig^T @ Wout).   q/k/v never materialized.
// R3: atomics removed (WRITE_SIZE showed 33.5MB of write-through atomic drain).
//     k_sgemm: 2 phases of BK=256 (128 KiB LDS) instead of 8 barrier-stages;
//     fp32 partials + k_sred 32-way reduce.

#define B_   4
#define HW_  16384
#define C_   256

typedef __attribute__((ext_vector_type(8))) short short8;
typedef __attribute__((ext_vector_type(4))) float floatx4;

__device__ __forceinline__ unsigned short f2bf(float f) {
  unsigned u = __builtin_bit_cast(unsigned, f);
  u += 0x7FFFu + ((u >> 16) & 1u);          // round-to-nearest-even
  return (unsigned short)(u >> 16);
}

__device__ __forceinline__ void gl_lds16(const unsigned short* g, unsigned short* l) {
  __builtin_amdgcn_global_load_lds(
      (const __attribute__((address_space(1))) unsigned int*)g,
      (__attribute__((address_space(3))) unsigned int*)l, 16, 0, 0);
}

// ---------------------------------------------------------------------------
// K1: cast fp32 -> bf16, emit xb (row-major [b*hw][c]) and xT ([b][c][hw]).
// grid 4096 = b(4) * ptile(256) * ctile(4), 256 thr. 64x64 tiles via LDS.
// ---------------------------------------------------------------------------
__global__ __launch_bounds__(256) void k_cast_tr(const float* __restrict__ x,
                                                 unsigned short* __restrict__ xb,
                                                 unsigned short* __restrict__ xT) {
  __shared__ unsigned short lds[64][72];
  int bid = blockIdx.x;
  int t = threadIdx.x;
  int ct = bid & 3;
  int pt = (bid >> 2) & 255;
  int b  = bid >> 10;
  const float* src = x + ((size_t)(b * HW_ + pt * 64)) * C_ + ct * 64;
#pragma unroll
  for (int e = 0; e < 4; e++) {
    int lin = t + e * 256;          // (p, c4)
    int p = lin >> 4, c4 = lin & 15;
    float4 v = *(const float4*)(src + (size_t)p * C_ + c4 * 4);
    ushort4 h;
    h.x = f2bf(v.x); h.y = f2bf(v.y); h.z = f2bf(v.z); h.w = f2bf(v.w);
    *(ushort4*)(xb + ((size_t)(b * HW_ + pt * 64 + p)) * C_ + ct * 64 + c4 * 4) = h;
    lds[c4 * 4 + 0][p] = h.x;
    lds[c4 * 4 + 1][p] = h.y;
    lds[c4 * 4 + 2][p] = h.z;
    lds[c4 * 4 + 3][p] = h.w;
  }
  __syncthreads();
#pragma unroll
  for (int e = 0; e < 4; e++) {
    int lin = t + e * 256;          // (c, p4)
    int c = lin >> 4, p4 = lin & 15;
    ushort4 h;
    h.x = lds[c][p4 * 4 + 0];
    h.y = lds[c][p4 * 4 + 1];
    h.z = lds[c][p4 * 4 + 2];
    h.w = lds[c][p4 * 4 + 3];
    *(ushort4*)(xT + ((size_t)(b * C_ + ct * 64 + c)) * HW_ + pt * 64 + p4 * 4) = h;
  }
}

// ---------------------------------------------------------------------------
// K2: S partials. grid 512 = b(4)*mt(2)*nt(2)*ks(32). Each block: 128x128 tile
// over K-chunk 512, done as 2 phases of BK=256 with 128 KiB LDS (only 2
// barrier drains per block). LDS rows are 256 bf16 = 32 octets (16B units),
// xor-swizzled: slot s of row r holds global octet s ^ (r&31), so both the
// wave-uniform global_load_lds scatter and the ds_read_b128 fragment reads
// stay at the free 2-way bank aliasing level.
// ---------------------------------------------------------------------------
__global__ __launch_bounds__(256) void k_sgemm(const unsigned short* __restrict__ xT,
                                               float* __restrict__ part) {
  __shared__ unsigned short At[128 * 256];   // 64 KiB
  __shared__ unsigned short Bt[128 * 256];   // 64 KiB
  int bid = blockIdx.x;
  int ks = bid & 31, nt = (bid >> 5) & 1, mt = (bid >> 6) & 1, b = bid >> 7;
  const unsigned short* Ab = xT + ((size_t)(b * C_ + mt * 128)) * HW_ + ks * 512;
  const unsigned short* Bb = xT + ((size_t)(b * C_ + nt * 128)) * HW_ + ks * 512;
  int t = threadIdx.x, lane = t & 63, w = t >> 6;
  int wm = w >> 1, wn = w & 1;
  int l15 = lane & 15, l4 = lane >> 4;
  int lrow = lane >> 5;           // row within a 2-row issue
  int lslot = lane & 31;          // LDS octet slot this lane fills
  floatx4 acc[4][4];
  floatx4 z = {0.f, 0.f, 0.f, 0.f};
#pragma unroll
  for (int i = 0; i < 4; i++)
#pragma unroll
    for (int j = 0; j < 4; j++) acc[i][j] = z;

  for (int ph = 0; ph < 2; ph++) {
    if (ph) __syncthreads();               // protect LDS reuse
    // stage 128 rows x 256 k per operand: 64 issues (1 KiB each), 16/wave
#pragma unroll
    for (int i = 0; i < 16; i++) {
      int issue = w * 16 + i;              // 0..63
      int row = issue * 2 + lrow;          // 0..127
      int goct = lslot ^ (row & 31);
      gl_lds16(Ab + (size_t)row * HW_ + ph * 256 + goct * 8, At + issue * 512);
      gl_lds16(Bb + (size_t)row * HW_ + ph * 256 + goct * 8, Bt + issue * 512);
    }
    __syncthreads();                       // drains vmcnt(0)
#pragma unroll
    for (int kk = 0; kk < 8; kk++) {       // 8 k-steps of 32 per phase
      short8 af[4], bfv[4];
      int oct = kk * 4 + l4;
#pragma unroll
      for (int tm = 0; tm < 4; tm++) {
        int row = wm * 64 + tm * 16 + l15;
        af[tm] = *(const short8*)(At + row * 256 + ((oct ^ (row & 31)) * 8));
      }
#pragma unroll
      for (int tn = 0; tn < 4; tn++) {
        int row = wn * 64 + tn * 16 + l15;
        bfv[tn] = *(const short8*)(Bt + row * 256 + ((oct ^ (row & 31)) * 8));
      }
#pragma unroll
      for (int tm = 0; tm < 4; tm++)
#pragma unroll
        for (int tn = 0; tn < 4; tn++)
          acc[tm][tn] = __builtin_amdgcn_mfma_f32_16x16x32_bf16(af[tm], bfv[tn],
                                                                acc[tm][tn], 0, 0, 0);
    }
  }
  // epilogue: streaming fp32 partial tile (coalesced 64B segments)
  float* pb = part + (size_t)bid * 16384;
#pragma unroll
  for (int tm = 0; tm < 4; tm++)
#pragma unroll
    for (int tn = 0; tn < 4; tn++)
#pragma unroll
      for (int r = 0; r < 4; r++) {
        int m = wm * 64 + tm * 16 + l4 * 4 + r;   // C/D: row=(lane>>4)*4+reg
        int n = wn * 64 + tn * 16 + l15;          //      col=lane&15
        pb[m * 128 + n] = acc[tm][tn][r];
      }
}

// K2r: reduce 32 K-partials -> S fp32 [b][256][256]. grid 1024 x 256.
__global__ __launch_bounds__(256) void k_sred(const float* __restrict__ part,
                                              float* __restrict__ S) {
  int idx = blockIdx.x * 256 + threadIdx.x;   // 0..262143
  int b = idx >> 16;
  int m = (idx >> 8) & 255, n = idx & 255;
  const float* p = part + ((size_t)((b * 4 + (m >> 7) * 2 + (n >> 7)) * 32)) * 16384
                   + (m & 127) * 128 + (n & 127);
  float s = 0.f;
#pragma unroll
  for (int k = 0; k < 32; k++) s += p[k * 16384];
  S[idx] = s;
}

// ---------------------------------------------------------------------------
// K3a: SWq = S@Wq, SWk = S@Wk (fp32, 64x64 tiles). grid 128 = b(4)*mt(4)*nt(8).
// ---------------------------------------------------------------------------
__global__ __launch_bounds__(256) void k_gemm_sw(const float* __restrict__ S,
                                                 const float* __restrict__ Wq,
                                                 const float* __restrict__ Wk,
                                                 float* __restrict__ SWq,
                                                 float* __restrict__ SWk) {
  __shared__ float As[64][17];
  __shared__ float Bs[16][65];
  int bid = blockIdx.x;
  int nt = bid & 7, mt = (bid >> 3) & 3, b = bid >> 5;
  int mb = mt * 64;
  const float* Wsel = (nt < 4) ? Wq : Wk;
  int nb = (nt & 3) * 64;
  int t = threadIdx.x, tx = t & 15, ty = t >> 4;
  float acc[4][4] = {};
  for (int kt = 0; kt < 16; kt++) {
    {
      int row = t >> 2, kq = t & 3;
      float4 v = *(const float4*)(S + ((size_t)(b * C_ + mb + row)) * C_ + kt * 16 + kq * 4);
      As[row][kq * 4 + 0] = v.x; As[row][kq * 4 + 1] = v.y;
      As[row][kq * 4 + 2] = v.z; As[row][kq * 4 + 3] = v.w;
    }
    {
      int kk = t >> 4, n4 = t & 15;
      float4 v = *(const float4*)(Wsel + ((size_t)(kt * 16 + kk)) * C_ + nb + n4 * 4);
      Bs[kk][n4 * 4 + 0] = v.x; Bs[kk][n4 * 4 + 1] = v.y;
      Bs[kk][n4 * 4 + 2] = v.z; Bs[kk][n4 * 4 + 3] = v.w;
    }
    __syncthreads();
#pragma unroll
    for (int k = 0; k < 16; k++) {
      float a[4], bb[4];
#pragma unroll
      for (int i = 0; i < 4; i++) a[i] = As[ty * 4 + i][k];
#pragma unroll
      for (int j = 0; j < 4; j++) bb[j] = Bs[k][tx * 4 + j];
#pragma unroll
      for (int i = 0; i < 4; i++)
#pragma unroll
        for (int j = 0; j < 4; j++) acc[i][j] += a[i] * bb[j];
    }
    __syncthreads();
  }
#pragma unroll
  for (int i = 0; i < 4; i++)
#pragma unroll
    for (int j = 0; j < 4; j++) {
      int row = mb + ty * 4 + i;
      int ng = nt * 64 + tx * 4 + j;
      if (ng < 256) SWq[((size_t)(b * C_ + row)) * C_ + ng] = acc[i][j];
      else          SWk[((size_t)(b * C_ + row)) * C_ + ng - 256] = acc[i][j];
    }
}

// ---------------------------------------------------------------------------
// K3f: fused G_h + norms + softmax + U_h. grid 32 = (b,h), 256 thr.
// ---------------------------------------------------------------------------
__global__ __launch_bounds__(256) void k_fuse(const float* __restrict__ Wq,
                                              const float* __restrict__ Wk,
                                              const float* __restrict__ SWq,
                                              const float* __restrict__ SWk,
                                              const float* __restrict__ Wout,
                                              float* __restrict__ U) {
  __shared__ float Wqh[256][32];    // 32 KiB (reused as Wo[32][256] for U phase)
  __shared__ float Wkh[256][32];
  __shared__ float SWqh[256][32];
  __shared__ float SWkh[256][32];   // total 128 KiB
  __shared__ float Lg[32][33];
  __shared__ float qp[8][32], kp[8][32], qin[32], kin[32];
  int b = blockIdx.x >> 3, h = blockIdx.x & 7;
  int t = threadIdx.x;
  int col = t & 31, rgrp = t >> 5;               // 8 rows per sweep
  for (int r0 = 0; r0 < 256; r0 += 8) {
    int row = r0 + rgrp;
    Wqh[row][col]  = Wq[(size_t)row * C_ + h * 32 + col];
    Wkh[row][col]  = Wk[(size_t)row * C_ + h * 32 + col];
    SWqh[row][col] = SWq[((size_t)(b * C_ + row)) * C_ + h * 32 + col];
    SWkh[row][col] = SWk[((size_t)(b * C_ + row)) * C_ + h * 32 + col];
  }
  __syncthreads();
  {
    float g[4] = {0.f, 0.f, 0.f, 0.f};
    for (int k = 0; k < 256; k++) {
      float swk = SWkh[k][col];
#pragma unroll
      for (int r = 0; r < 4; r++) g[r] += Wqh[k][rgrp + 8 * r] * swk;
    }
#pragma unroll
    for (int r = 0; r < 4; r++) Lg[rgrp + 8 * r][col] = g[r];
  }
  {
    float sq = 0.f, sk = 0.f;
    for (int k = rgrp * 32; k < rgrp * 32 + 32; k++) {
      sq += Wqh[k][col] * SWqh[k][col];
      sk += Wkh[k][col] * SWkh[k][col];
    }
    qp[rgrp][col] = sq;
    kp[rgrp][col] = sk;
  }
  __syncthreads();
  if (t < 32) {
    float a = 0.f;
#pragma unroll
    for (int p = 0; p < 8; p++) a += qp[p][t];
    qin[t] = rsqrtf(a);
  } else if (t < 64) {
    int j = t - 32;
    float a = 0.f;
#pragma unroll
    for (int p = 0; p < 8; p++) a += kp[p][j];
    kin[j] = rsqrtf(a);
  }
  __syncthreads();
  if (t < 32) {
    float row[32];
    float mx = -1e30f;
#pragma unroll
    for (int j = 0; j < 32; j++) {
      row[j] = Lg[t][j] * qin[t] * kin[j] * 0.0078125f;   // /sqrt(16384)
      mx = fmaxf(mx, row[j]);
    }
    float sum = 0.f;
#pragma unroll
    for (int j = 0; j < 32; j++) { row[j] = __expf(row[j] - mx); sum += row[j]; }
    float inv = 1.0f / sum;
#pragma unroll
    for (int j = 0; j < 32; j++) Lg[t][j] = row[j] * inv;
  }
  __syncthreads();
  float (*Wo)[256] = reinterpret_cast<float(*)[256]>(&Wqh[0][0]);
#pragma unroll
  for (int r = 0; r < 32; r++) Wo[r][t] = Wout[((size_t)(h * 32 + r)) * C_ + t];
  __syncthreads();
  for (int j = 0; j < 32; j++) {
    float a = 0.f;
#pragma unroll
    for (int i2 = 0; i2 < 32; i2++) a += Lg[i2][j] * Wo[i2][t];
    U[((size_t)(b * C_ + h * 32 + j)) * C_ + t] = a;
  }
}

// ---------------------------------------------------------------------------
// K3e: W3 = Wv @ U[b], emitted transposed bf16: W3bT[b][n][c]. grid 64.
// ---------------------------------------------------------------------------
__global__ __launch_bounds__(256) void k_gemm_w3(const float* __restrict__ Wv,
                                                 const float* __restrict__ U,
                                                 unsigned short* __restrict__ W3bT) {
  __shared__ float As[64][17];
  __shared__ float Bs[16][65];
  int bid = blockIdx.x;
  int nt = bid & 3, mt = (bid >> 2) & 3, b = bid >> 4;
  int mb = mt * 64, nb = nt * 64;
  int t = threadIdx.x, tx = t & 15, ty = t >> 4;
  float acc[4][4] = {};
  for (int kt = 0; kt < 16; kt++) {
    {
      int row = t >> 2, kq = t & 3;
      float4 v = *(const float4*)(Wv + ((size_t)(mb + row)) * C_ + kt * 16 + kq * 4);
      As[row][kq * 4 + 0] = v.x; As[row][kq * 4 + 1] = v.y;
      As[row][kq * 4 + 2] = v.z; As[row][kq * 4 + 3] = v.w;
    }
    {
      int kk = t >> 4, n4 = t & 15;
      float4 v = *(const float4*)(U + ((size_t)(b * C_ + kt * 16 + kk)) * C_ + nb + n4 * 4);
      Bs[kk][n4 * 4 + 0] = v.x; Bs[kk][n4 * 4 + 1] = v.y;
      Bs[kk][n4 * 4 + 2] = v.z; Bs[kk][n4 * 4 + 3] = v.w;
    }
    __syncthreads();
#pragma unroll
    for (int k = 0; k < 16; k++) {
      float a[4], bb[4];
#pragma unroll
      for (int i = 0; i < 4; i++) a[i] = As[ty * 4 + i][k];
#pragma unroll
      for (int j = 0; j < 4; j++) bb[j] = Bs[k][tx * 4 + j];
#pragma unroll
      for (int i = 0; i < 4; i++)
#pragma unroll
        for (int j = 0; j < 4; j++) acc[i][j] += a[i] * bb[j];
    }
    __syncthreads();
  }
#pragma unroll
  for (int i = 0; i < 4; i++)
#pragma unroll
    for (int j = 0; j < 4; j++)
      W3bT[((size_t)(b * C_ + nb + tx * 4 + j)) * C_ + mb + ty * 4 + i] = f2bf(acc[i][j]);
}

// ---------------------------------------------------------------------------
// K4: out = xb @ W3[b], fp32 out. grid 1024 = mtile(512)*ntile(2).
// BK=64, 4 stages via the classic swizzled glds path (8-slot rows).
// ---------------------------------------------------------------------------
__global__ __launch_bounds__(256) void k_out(const unsigned short* __restrict__ xb,
                                             const unsigned short* __restrict__ W3bT,
                                             float* __restrict__ out) {
  __shared__ unsigned short At[128 * 64];
  __shared__ unsigned short Bt[128 * 64];
  int bid = blockIdx.x;
  int ntile = bid & 1, mtile = bid >> 1;
  int b = mtile >> 7;
  const unsigned short* Ab = xb + (size_t)mtile * 128 * C_;
  const unsigned short* Bb = W3bT + ((size_t)(b * C_ + ntile * 128)) * C_;
  int t = threadIdx.x, lane = t & 63, w = t >> 6;
  int wm = w >> 1, wn = w & 1;
  int l8 = lane >> 3, l7 = lane & 7;
  int srcoct = l7 ^ l8;
  int l15 = lane & 15, l4 = lane >> 4;
  floatx4 acc[4][4];
  floatx4 z = {0.f, 0.f, 0.f, 0.f};
#pragma unroll
  for (int i = 0; i < 4; i++)
#pragma unroll
    for (int j = 0; j < 4; j++) acc[i][j] = z;
  for (int s = 0; s < 4; s++) {
    if (s) __syncthreads();
#pragma unroll
    for (int i = 0; i < 4; i++) {
      int gi = w * 4 + i;
      int row = gi * 8 + l8;
      gl_lds16(Ab + (size_t)row * C_ + s * 64 + srcoct * 8, At + gi * 512);
      gl_lds16(Bb + (size_t)row * C_ + s * 64 + srcoct * 8, Bt + gi * 512);
    }
    __syncthreads();
#pragma unroll
    for (int kk = 0; kk < 2; kk++) {
      short8 af[4], bfv[4];
#pragma unroll
      for (int tm = 0; tm < 4; tm++) {
        int row = wm * 64 + tm * 16 + l15;
        int oct = kk * 4 + l4;
        af[tm] = *(const short8*)(At + row * 64 + ((oct ^ (l15 & 7)) * 8));
      }
#pragma unroll
      for (int tn = 0; tn < 4; tn++) {
        int row = wn * 64 + tn * 16 + l15;
        int oct = kk * 4 + l4;
        bfv[tn] = *(const short8*)(Bt + row * 64 + ((oct ^ (l15 & 7)) * 8));
      }
#pragma unroll
      for (int tm = 0; tm < 4; tm++)
#pragma unroll
        for (int tn = 0; tn < 4; tn++)
          acc[tm][tn] = __builtin_amdgcn_mfma_f32_16x16x32_bf16(af[tm], bfv[tn],
                                                                acc[tm][tn], 0, 0, 0);
    }
  }
  float* ob = out + (size_t)mtile * 128 * C_ + ntile * 128;
#pragma unroll
  for (int tm = 0; tm < 4; tm++)
#pragma unroll
    for (int tn = 0; tn < 4; tn++)
#pragma unroll
      for (int r = 0; r < 4; r++) {
        int m = wm * 64 + tm * 16 + l4 * 4 + r;
        int n = wn * 64 + tn * 16 + l15;
        ob[(size_t)m * C_ + n] = acc[tm][tn][r];
      }
}

// ---------------------------------------------------------------------------
extern "C" void kernel_launch(void* const* d_in, const int* in_sizes, int n_in,
                              void* d_out, int out_size, void* d_ws, size_t ws_size,
                              hipStream_t stream) {
  const float* x    = (const float*)d_in[0];
  const float* Wq   = (const float*)d_in[1];
  const float* Wk   = (const float*)d_in[2];
  const float* Wv   = (const float*)d_in[3];
  const float* Wout = (const float*)d_in[4];
  float* out = (float*)d_out;

  // workspace carve-up (~100.5 MiB)
  unsigned short* xT = (unsigned short*)d_ws;          // 4*256*16384 bf16 = 32 MiB
  unsigned short* xb = xT + (size_t)16777216;          // 32 MiB
  float* part = (float*)(xb + (size_t)16777216);       // 512*128*128 fp32 = 32 MiB
  float* S    = part + (size_t)8388608;                // 1 MiB
  float* SWq  = S + 262144;                            // 1 MiB
  float* SWk  = SWq + 262144;                          // 1 MiB
  float* U    = SWk + 262144;                          // 1 MiB
  unsigned short* W3bT = (unsigned short*)(U + 262144); // 512 KiB

  k_cast_tr<<<dim3(4096), dim3(256), 0, stream>>>(x, xb, xT);
  k_sgemm<<<dim3(512), dim3(256), 0, stream>>>(xT, part);
  k_sred<<<dim3(1024), dim3(256), 0, stream>>>(part, S);
  k_gemm_sw<<<dim3(128), dim3(256), 0, stream>>>(S, Wq, Wk, SWq, SWk);
  k_fuse<<<dim3(32), dim3(256), 0, stream>>>(Wq, Wk, SWq, SWk, Wout, U);
  k_gemm_w3<<<dim3(64), dim3(256), 0, stream>>>(Wv, U, W3bT);
  k_out<<<dim3(1024), dim3(256), 0, stream>>>(xb, W3bT, out);
}